// Round 27
// baseline (141.773 us; speedup 1.0000x reference)
//
#include <hip/hip_runtime.h>
#include <hip/hip_bf16.h>

#define DEVI __device__ __forceinline__

constexpr int Bc = 2, Cc = 64, Tc = 4, Hc = 64, Wc = 64, OFFc = 54, KVc = 27;
constexpr int HW  = Hc * Wc;     // 4096
constexpr int THW = Tc * HW;     // 16384

typedef __attribute__((ext_vector_type(8))) short bf16x8;
typedef __attribute__((ext_vector_type(4))) float f32x4;

DEVI short f2bf(float f) {
    __hip_bfloat16 h = __float2bfloat16(f);
    return *reinterpret_cast<short*>(&h);
}
DEVI float bf2f(short s) {
    unsigned u = ((unsigned)(unsigned short)s) << 16;
    float f; __builtin_memcpy(&f, &u, 4); return f;
}

// ------- all 4 weight buffers -> K-major MFMA A layout, one dispatch -------
__global__ __launch_bounds__(256) void w_prep4(
    const float* __restrict__ w0, const float* __restrict__ w1,
    const float* __restrict__ w2, const float* __restrict__ w3,
    __hip_bfloat16* __restrict__ d0, __hip_bfloat16* __restrict__ d1,
    __hip_bfloat16* __restrict__ d2, __hip_bfloat16* __restrict__ d3)
{
    int gi = blockIdx.x;
    int seg = gi / 432;
    int i = (gi - seg * 432) * 256 + threadIdx.x;   // 216*512 = 110592
    if (i >= 216 * 512) return;
    const float* w = seg == 0 ? w0 : seg == 1 ? w1 : seg == 2 ? w2 : w3;
    __hip_bfloat16* dst = seg == 0 ? d0 : seg == 1 ? d1 : seg == 2 ? d2 : d3;
    int ovalid = (seg < 2) ? OFFc : Cc;
    int u = i >> 9, r = i & 511;
    int mf = u & 3, ch = (u >> 2) & 1, tap = u >> 3;
    int o = mf * 16 + (r >> 5), c = ch * 32 + (r & 31);
    float v = (o < ovalid) ? w[(o * Cc + c) * KVc + tap] : 0.f;
    dst[i] = __float2bfloat16(v);
}

// ------- cast + transpose to channel-last bf16 -------
__global__ __launch_bounds__(256) void cast_cl(const float* __restrict__ x,
                                               __hip_bfloat16* __restrict__ xcl) {
    __shared__ float s[64][65];
    int tid = threadIdx.x;
    int bi  = blockIdx.x;
    int h = bi & 63, t = (bi >> 6) & 3, b = bi >> 8;

    const float* xp = x + (size_t)b * Cc * THW + t * HW + h * 64;
    int w0 = tid & 63, c0 = tid >> 6;
    #pragma unroll
    for (int i = 0; i < 16; ++i) {
        int c = c0 + i * 4;
        s[c][w0] = xp[(size_t)c * THW + w0];
    }
    __syncthreads();

    __hip_bfloat16* dst = xcl + (((size_t)b * Tc + t) * HW + (size_t)h * 64) * 64;
    #pragma unroll
    for (int r = 0; r < 2; ++r) {
        int j  = tid + r * 256;
        int w  = j >> 3;
        int c8 = j & 7;
        bf16x8 v;
        #pragma unroll
        for (int jj = 0; jj < 8; ++jj)
            v[jj] = f2bf(s[c8 * 8 + jj][w]);
        *reinterpret_cast<bf16x8*>(dst + w * 64 + c8 * 8) = v;
    }
}

// ===== fused offset-conv + deformable-conv: tap-parity waves, full-K per wave =====
// Geometry: block = (b,t,h-pair,whalf), 64 positions, 512 thr = 8 waves =
// nf(4 pos-groups) x th(2 tap-parity). Each wave handles BOTH channel halves
// (8 MFMAs/tap, 2 ldreads/corner) over HALF the taps -> per-tap coefficient /
// s_off-read / addressing VALU is computed once instead of twice (was per-chh).
// Atomic-free reductions keyed by th (R25/R26-proven); reduce stores f32x4.
constexpr int WT = 40;            // tile w-columns, covers global w in [wb-3, wb+36]
constexpr int RSTRIDE = WT * 128; // 5120 bytes per tile row
constexpr int OFFB = 14256;       // bytes per s_off region ([27][2][66] f32)

template <bool L2>
__global__ __launch_bounds__(512, 2) void fused_deform(
    const __hip_bfloat16* __restrict__ src, const __hip_bfloat16* __restrict__ owAk,
    const float* __restrict__ obias, const __hip_bfloat16* __restrict__ wAk,
    const float* __restrict__ xres, float* __restrict__ outf,
    __hip_bfloat16* __restrict__ ycl)
{
    __shared__ __align__(16) char s_mem[6 * RSTRIDE + 2 * OFFB];
    short* s_tile = (short*)s_mem;                            // swizzled tile [6][40][64ch]
    float* sp0    = (float*)(s_mem + 6 * RSTRIDE);            // th=0 partials -> canonical s_off
    float* sp1    = (float*)(s_mem + 6 * RSTRIDE + OFFB);     // th=1 partials
    float* s_off  = sp0;                                      // after merge
    float* red0 = (float*)s_mem;                              // [64][68] th=0 partials (aliases tile)
    float* red1 = (float*)s_mem + 64 * 68;                    // [64][68] th=1 partials

    int tid = threadIdx.x;
    int wv = tid >> 6, lane = tid & 63, l15 = lane & 15, l4 = lane >> 4;
    int nf = wv & 3, th = wv >> 2;

    // ---- balanced plane-pair -> XCD decode ----
    int bi = blockIdx.x;
    int xcd = bi & 7, idx = bi >> 3;          // idx in [0,64)
    int jgrp = xcd >> 1, whalf = xcd & 1;     // job = (b, t-pair); w-half per XCD
    int b = jgrp >> 1;
    int h2 = idx & 31;                        // h-pair index
    int tsel = (idx >> 5) & 1;                // per-CU light/heavy interleave
    int t = ((jgrp & 1) << 1) + tsel;         // t-pair {0,1} or {2,3}
    int h0 = h2 * 2;
    int wb = whalf * 32;

    int pl = nf * 16 + l15;               // local position 0..63 (2 rows x 32 w)
    int prow = pl >> 5, pcol = pl & 31;
    int hr = h0 + prow;                   // this lane's output h row
    int p  = wb + pcol;                   // global w position
    int cb0 = l4 * 8, cb1 = 32 + l4 * 8;  // the two channel slices (both handled here)
    int ktlo = (t == 0) ? 1 : 0, kthi = (t == 3) ? 2 : 3;

    const __hip_bfloat16* xb = src + ((size_t)b << 20);

    auto stage = [&](int kt) {
        int tt = t + kt - 1;   // valid by loop range
        const __hip_bfloat16* xt = xb + ((size_t)tt << 18);
        for (int i = tid; i < 6 * WT * 8; i += 512) {
            int r = i / (WT * 8), v = i - r * (WT * 8);
            int wl = v >> 3, ss = v & 7;
            int hh = h0 - 2 + r;
            int wg = wb - 3 + wl;
            bf16x8 val = {0, 0, 0, 0, 0, 0, 0, 0};
            if ((unsigned)hh < 64u && (unsigned)wg < 64u)
                val = *reinterpret_cast<const bf16x8*>(xt + ((hh * 64 + wg) << 6) + ss * 8);
            int byte = (r * RSTRIDE + wl * 128 + ss * 16) ^ ((wl & 7) << 4);
            *reinterpret_cast<bf16x8*>((char*)s_tile + byte) = val;
        }
    };
    auto ldread = [&](int sl, int wg, int cb) -> bf16x8 {   // wg = clamped global w (in window)
        int wl = wg - (wb - 3);
        int byte = (sl * RSTRIDE + wl * 128 + cb * 2) ^ ((wl & 7) << 4);
        return *reinterpret_cast<const bf16x8*>((const char*)s_tile + byte);
    };

    // ================= pass A: offset conv (parity-split taps, full K per wave) =====
    f32x4 cacc[4];
    #pragma unroll
    for (int mf = 0; mf < 4; ++mf) cacc[mf] = (f32x4){0.f, 0.f, 0.f, 0.f};

    for (int kt = ktlo; kt < kthi; ++kt) {
        __syncthreads();
        stage(kt);
        __syncthreads();
        int rr0 = (th + kt) & 1;
        #pragma clang loop unroll(disable)
        for (int rr = rr0; rr < 9; rr += 2) {
            int kh = rr / 3, kw = rr - kh * 3, tap = kt * 9 + rr;
            int ws = p + kw - 1;
            int wsc = min(max(ws, 0), 63);
            bf16x8 bv0 = ldread(prow + kh + 1, wsc, cb0);
            bf16x8 bv1 = ldread(prow + kh + 1, wsc, cb1);
            if ((unsigned)ws >= 64u) {
                bv0 = (bf16x8){0, 0, 0, 0, 0, 0, 0, 0};
                bv1 = (bf16x8){0, 0, 0, 0, 0, 0, 0, 0};
            }
            const __hip_bfloat16* ab0 = owAk + ((tap * 2 + 0) << 11) + (l15 << 5) + (l4 << 3);
            const __hip_bfloat16* ab1 = owAk + ((tap * 2 + 1) << 11) + (l15 << 5) + (l4 << 3);
            #pragma unroll
            for (int mf = 0; mf < 4; ++mf) {
                bf16x8 af0 = *reinterpret_cast<const bf16x8*>(ab0 + (mf << 9));
                bf16x8 af1 = *reinterpret_cast<const bf16x8*>(ab1 + (mf << 9));
                cacc[mf] = __builtin_amdgcn_mfma_f32_16x16x32_bf16(af0, bv0, cacc[mf], 0, 0, 0);
                cacc[mf] = __builtin_amdgcn_mfma_f32_16x16x32_bf16(af1, bv1, cacc[mf], 0, 0, 0);
            }
        }
    }
    // ---- atomic-free s_off reduction: plain stores to per-th partial region ----
    {
        float* sp = th ? sp1 : sp0;
        #pragma unroll
        for (int mf = 0; mf < 4; ++mf)
            #pragma unroll
            for (int jj = 0; jj < 4; ++jj) {
                int o = mf * 16 + l4 * 4 + jj;
                if (o < OFFc) sp[o * 66 + pl] = cacc[mf][jj];   // (o>>1)*132+(o&1)*66 == o*66
            }
    }
    __syncthreads();
    // ---- merge: s_off = sp0 + sp1 + bias ----
    for (int i = tid; i < KVc * 2 * 66; i += 512) {
        int k = i / 132, rem = i - k * 132, jo = rem / 66;
        sp0[i] = sp0[i] + sp1[i] + obias[2 * k + jo];
    }

    // ================= pass B: deformable conv (parity-split taps, full K) =====
    f32x4 dacc[4];
    #pragma unroll
    for (int mf = 0; mf < 4; ++mf) dacc[mf] = (f32x4){0.f, 0.f, 0.f, 0.f};

    unsigned badmask = 0;

    for (int kt = kthi - 1; kt >= ktlo; --kt) {
        __syncthreads();     // first iter: guards s_off merge; tile already holds kthi-1
        if (kt != kthi - 1) {
            stage(kt);
            __syncthreads();
        }
        int rr0 = (th + kt) & 1;
        #pragma clang loop unroll(disable)
        for (int rr = rr0; rr < 9; rr += 2) {
            int kh = rr / 3, kw = rr - kh * 3, tap = kt * 9 + rr;
            float dh = s_off[tap * 132 + pl];
            float dw = s_off[tap * 132 + 66 + pl];
            float hs  = (float)(hr + kh - 1) + dh;
            float wsf = (float)(p + kw - 1) + dw;
            float fh = floorf(hs), fw = floorf(wsf);
            int hfl = (int)fh, w0 = (int)fw;
            float lh = hs - fh, lw = wsf - fw;
            float q0 = (1.f - lw) * (((unsigned)w0 < 64u) ? 1.f : 0.f);
            float q1 = lw         * (((unsigned)(w0 + 1) < 64u) ? 1.f : 0.f);
            int wc0 = min(max(w0, 0), 63), wc1 = min(max(w0 + 1, 0), 63);
            int r0 = hfl - (h0 - 2);
            int r0c = min(max(r0, 0), 4);
            badmask |= ((r0 != r0c) ? 1u : 0u) << tap;
            bf16x8 g0a = ldread(r0c, wc0, cb0),     g0b = ldread(r0c, wc0, cb1);
            bf16x8 g1a = ldread(r0c, wc1, cb0),     g1b = ldread(r0c, wc1, cb1);
            bf16x8 g2a = ldread(r0c + 1, wc0, cb0), g2b = ldread(r0c + 1, wc0, cb1);
            bf16x8 g3a = ldread(r0c + 1, wc1, cb0), g3b = ldread(r0c + 1, wc1, cb1);
            float cf0 = (1.f - lh) * q0, cf1 = (1.f - lh) * q1;
            float cf2 = lh * q0,         cf3 = lh * q1;
            bf16x8 bfr0, bfr1;
            #pragma unroll
            for (int jj = 0; jj < 8; ++jj) {
                float s0 = cf0 * bf2f(g0a[jj]) + cf1 * bf2f(g1a[jj])
                         + cf2 * bf2f(g2a[jj]) + cf3 * bf2f(g3a[jj]);
                float s1 = cf0 * bf2f(g0b[jj]) + cf1 * bf2f(g1b[jj])
                         + cf2 * bf2f(g2b[jj]) + cf3 * bf2f(g3b[jj]);
                bfr0[jj] = f2bf(s0);
                bfr1[jj] = f2bf(s1);
            }
            const __hip_bfloat16* ab0 = wAk + ((tap * 2 + 0) << 11) + (l15 << 5) + (l4 << 3);
            const __hip_bfloat16* ab1 = wAk + ((tap * 2 + 1) << 11) + (l15 << 5) + (l4 << 3);
            #pragma unroll
            for (int mf = 0; mf < 4; ++mf) {
                bf16x8 af0 = *reinterpret_cast<const bf16x8*>(ab0 + (mf << 9));
                bf16x8 af1 = *reinterpret_cast<const bf16x8*>(ab1 + (mf << 9));
                dacc[mf] = __builtin_amdgcn_mfma_f32_16x16x32_bf16(af0, bfr0, dacc[mf], 0, 0, 0);
                dacc[mf] = __builtin_amdgcn_mfma_f32_16x16x32_bf16(af1, bfr1, dacc[mf], 0, 0, 0);
            }
        }
    }

    // ---- exact correction for window misses (cold; never taken for ~0.02-scale offsets) ----
    if (__any((int)(badmask != 0u))) {
        for (int kt = ktlo; kt < kthi; ++kt) {
            int tt = t + kt - 1;
            const __hip_bfloat16* xt = xb + ((size_t)tt << 18);
            int rr0 = (th + kt) & 1;
            #pragma clang loop unroll(disable)
            for (int rr = rr0; rr < 9; rr += 2) {
                int tap = kt * 9 + rr;
                if (!__any((int)((badmask >> tap) & 1u))) continue;
                int kh = rr / 3, kw = rr - kh * 3;
                float dh = s_off[tap * 132 + pl];
                float dw = s_off[tap * 132 + 66 + pl];
                float hs  = (float)(hr + kh - 1) + dh;
                float wsf = (float)(p + kw - 1) + dw;
                float fh = floorf(hs), fw = floorf(wsf);
                int hfl = (int)fh, w0 = (int)fw;
                float lh = hs - fh, lw = wsf - fw;
                float q0 = (1.f - lw) * (((unsigned)w0 < 64u) ? 1.f : 0.f);
                float q1 = lw         * (((unsigned)(w0 + 1) < 64u) ? 1.f : 0.f);
                int wc0 = min(max(w0, 0), 63), wc1 = min(max(w0 + 1, 0), 63);
                int r0 = hfl - (h0 - 2);
                int r0c = min(max(r0, 0), 4);
                bool bad = ((badmask >> tap) & 1u) != 0u;
                float u0 = (1.f - lh) * (((unsigned)hfl < 64u) ? 1.f : 0.f);
                float u1 = lh         * (((unsigned)(hfl + 1) < 64u) ? 1.f : 0.f);
                int hc0 = min(max(hfl, 0), 63), hc1 = min(max(hfl + 1, 0), 63);
                int ra0 = h0 - 2 + r0c, ra1 = ra0 + 1;
                float m0 = ((unsigned)ra0 < 64u) ? 1.f : 0.f;
                float m1 = ((unsigned)ra1 < 64u) ? 1.f : 0.f;
                int rc0 = min(max(ra0, 0), 63), rc1 = min(max(ra1, 0), 63);
                #pragma unroll
                for (int half = 0; half < 2; ++half) {
                    int cb = half ? cb1 : cb0;
                    bf16x8 tg0 = *reinterpret_cast<const bf16x8*>(xt + ((hc0 * 64 + wc0) << 6) + cb);
                    bf16x8 tg1 = *reinterpret_cast<const bf16x8*>(xt + ((hc0 * 64 + wc1) << 6) + cb);
                    bf16x8 tg2 = *reinterpret_cast<const bf16x8*>(xt + ((hc1 * 64 + wc0) << 6) + cb);
                    bf16x8 tg3 = *reinterpret_cast<const bf16x8*>(xt + ((hc1 * 64 + wc1) << 6) + cb);
                    bf16x8 ag0 = *reinterpret_cast<const bf16x8*>(xt + ((rc0 * 64 + wc0) << 6) + cb);
                    bf16x8 ag1 = *reinterpret_cast<const bf16x8*>(xt + ((rc0 * 64 + wc1) << 6) + cb);
                    bf16x8 ag2 = *reinterpret_cast<const bf16x8*>(xt + ((rc1 * 64 + wc0) << 6) + cb);
                    bf16x8 ag3 = *reinterpret_cast<const bf16x8*>(xt + ((rc1 * 64 + wc1) << 6) + cb);
                    bf16x8 bfrag;
                    #pragma unroll
                    for (int jj = 0; jj < 8; ++jj) {
                        float ft = u0 * (q0 * bf2f(tg0[jj]) + q1 * bf2f(tg1[jj]))
                                 + u1 * (q0 * bf2f(tg2[jj]) + q1 * bf2f(tg3[jj]));
                        float fa = (1.f - lh) * m0 * (q0 * bf2f(ag0[jj]) + q1 * bf2f(ag1[jj]))
                                 + lh * m1 * (q0 * bf2f(ag2[jj]) + q1 * bf2f(ag3[jj]));
                        bfrag[jj] = f2bf(bad ? (ft - fa) : 0.f);
                    }
                    const __hip_bfloat16* ab = wAk + ((tap * 2 + half) << 11) + (l15 << 5) + (l4 << 3);
                    #pragma unroll
                    for (int mf = 0; mf < 4; ++mf) {
                        bf16x8 af = *reinterpret_cast<const bf16x8*>(ab + (mf << 9));
                        dacc[mf] = __builtin_amdgcn_mfma_f32_16x16x32_bf16(af, bfrag, dacc[mf], 0, 0, 0);
                    }
                }
            }
        }
    }

    // ---- atomic-free reduce: per-th partial regions, f32x4 stores (tile + s_off dead) ----
    __syncthreads();                       // all tile / s_off reads complete
    {
        float* red = th ? red1 : red0;
        #pragma unroll
        for (int mf = 0; mf < 4; ++mf)
            *reinterpret_cast<f32x4*>(&red[pl * 68 + mf * 16 + l4 * 4]) = dacc[mf];
    }
    __syncthreads();

    // ---- fused epilogue (sum the two th regions, vectorized reads) ----
    if (!L2) {
        // leaky-relu + channel-last bf16 store (64 pos x 64 ch)
        int pp = tid >> 3, o8 = (tid & 7) << 3;
        int er = pp >> 5, ew = pp & 31;
        __hip_bfloat16* dst = ycl + ((((size_t)b * Tc + t) * HW + (h0 + er) * 64 + wb + ew) << 6) + o8;
        bf16x8 o8v;
        #pragma unroll
        for (int q = 0; q < 2; ++q) {
            f32x4 v0 = *reinterpret_cast<const f32x4*>(&red0[pp * 68 + o8 + q * 4]);
            f32x4 v1 = *reinterpret_cast<const f32x4*>(&red1[pp * 68 + o8 + q * 4]);
            #pragma unroll
            for (int jj = 0; jj < 4; ++jj) {
                float v = v0[jj] + v1[jj];
                v = v >= 0.f ? v : 0.1f * v;
                o8v[q * 4 + jj] = f2bf(v);
            }
        }
        *reinterpret_cast<bf16x8*>(dst) = o8v;
    } else {
        // residual add + fp32 channel-first store
        int o = tid >> 3, pg = (tid & 7) << 3;   // 8 positions per thread, same row
        int er = pg >> 5, ew = pg & 31;
        size_t base = ((size_t)(b * Cc + o) * Tc + t) * HW + (h0 + er) * 64 + wb + ew;
        #pragma unroll
        for (int q = 0; q < 2; ++q) {
            f32x4 r, xv = *reinterpret_cast<const f32x4*>(xres + base + q * 4);
            #pragma unroll
            for (int jj = 0; jj < 4; ++jj) {
                int i = (pg + q * 4 + jj) * 68 + o;
                r[jj] = red0[i] + red1[i] + xv[jj];
            }
            *reinterpret_cast<f32x4*>(outf + base + q * 4) = r;
        }
    }
}

extern "C" void kernel_launch(void* const* d_in, const int* in_sizes, int n_in,
                              void* d_out, int out_size, void* d_ws, size_t ws_size,
                              hipStream_t stream)
{
    const float* x   = (const float*)d_in[0];
    const float* w0  = (const float*)d_in[1];
    const float* ow0 = (const float*)d_in[2];
    const float* ob0 = (const float*)d_in[3];
    const float* w1  = (const float*)d_in[4];
    const float* ow1 = (const float*)d_in[5];
    const float* ob1 = (const float*)d_in[6];
    float* out = (float*)d_out;

    __hip_bfloat16* xcl  = (__hip_bfloat16*)d_ws;
    __hip_bfloat16* ycl  = xcl  + (size_t)Bc * THW * 64;
    __hip_bfloat16* owA0 = ycl  + (size_t)Bc * THW * 64;
    __hip_bfloat16* owA1 = owA0 + (size_t)216 * 512;
    __hip_bfloat16* wA0  = owA1 + (size_t)216 * 512;
    __hip_bfloat16* wA1  = wA0  + (size_t)216 * 512;

    w_prep4<<<1728, 256, 0, stream>>>(ow0, ow1, w0, w1, owA0, owA1, wA0, wA1);
    cast_cl<<<512, 256, 0, stream>>>(x, xcl);

    fused_deform<false><<<512, 512, 0, stream>>>(xcl, owA0, ob0, wA0, nullptr, nullptr, ycl);
    fused_deform<true><<<512, 512, 0, stream>>>(ycl, owA1, ob1, wA1, x, out, nullptr);
}

// Round 28
// 114.970 us; speedup vs baseline: 1.2331x; 1.2331x over previous
//
#include <hip/hip_runtime.h>
#include <hip/hip_bf16.h>

#define DEVI __device__ __forceinline__

constexpr int Bc = 2, Cc = 64, Tc = 4, Hc = 64, Wc = 64, OFFc = 54, KVc = 27;
constexpr int HW  = Hc * Wc;     // 4096
constexpr int THW = Tc * HW;     // 16384

typedef __attribute__((ext_vector_type(8))) short bf16x8;
typedef __attribute__((ext_vector_type(4))) float f32x4;

DEVI short f2bf(float f) {
    __hip_bfloat16 h = __float2bfloat16(f);
    return *reinterpret_cast<short*>(&h);
}
DEVI float bf2f(short s) {
    unsigned u = ((unsigned)(unsigned short)s) << 16;
    float f; __builtin_memcpy(&f, &u, 4); return f;
}

// ------- all 4 weight buffers -> K-major MFMA A layout, one dispatch -------
__global__ __launch_bounds__(256) void w_prep4(
    const float* __restrict__ w0, const float* __restrict__ w1,
    const float* __restrict__ w2, const float* __restrict__ w3,
    __hip_bfloat16* __restrict__ d0, __hip_bfloat16* __restrict__ d1,
    __hip_bfloat16* __restrict__ d2, __hip_bfloat16* __restrict__ d3)
{
    int gi = blockIdx.x;
    int seg = gi / 432;
    int i = (gi - seg * 432) * 256 + threadIdx.x;   // 216*512 = 110592
    if (i >= 216 * 512) return;
    const float* w = seg == 0 ? w0 : seg == 1 ? w1 : seg == 2 ? w2 : w3;
    __hip_bfloat16* dst = seg == 0 ? d0 : seg == 1 ? d1 : seg == 2 ? d2 : d3;
    int ovalid = (seg < 2) ? OFFc : Cc;
    int u = i >> 9, r = i & 511;
    int mf = u & 3, ch = (u >> 2) & 1, tap = u >> 3;
    int o = mf * 16 + (r >> 5), c = ch * 32 + (r & 31);
    float v = (o < ovalid) ? w[(o * Cc + c) * KVc + tap] : 0.f;
    dst[i] = __float2bfloat16(v);
}

// ------- cast + transpose to channel-last bf16 -------
__global__ __launch_bounds__(256) void cast_cl(const float* __restrict__ x,
                                               __hip_bfloat16* __restrict__ xcl) {
    __shared__ float s[64][65];
    int tid = threadIdx.x;
    int bi  = blockIdx.x;
    int h = bi & 63, t = (bi >> 6) & 3, b = bi >> 8;

    const float* xp = x + (size_t)b * Cc * THW + t * HW + h * 64;
    int w0 = tid & 63, c0 = tid >> 6;
    #pragma unroll
    for (int i = 0; i < 16; ++i) {
        int c = c0 + i * 4;
        s[c][w0] = xp[(size_t)c * THW + w0];
    }
    __syncthreads();

    __hip_bfloat16* dst = xcl + (((size_t)b * Tc + t) * HW + (size_t)h * 64) * 64;
    #pragma unroll
    for (int r = 0; r < 2; ++r) {
        int j  = tid + r * 256;
        int w  = j >> 3;
        int c8 = j & 7;
        bf16x8 v;
        #pragma unroll
        for (int jj = 0; jj < 8; ++jj)
            v[jj] = f2bf(s[c8 * 8 + jj][w]);
        *reinterpret_cast<bf16x8*>(dst + w * 64 + c8 * 8) = v;
    }
}

// ===== fused offset-conv + deformable-conv, 2-row blocks, FULLY atomic-free =====
// R26-proven best (58.6us/dispatch): block = (b,t,h-pair,whalf), 64 positions,
// 512 thr = 8 waves = nf(4) x chh(2); balanced adjacent-t pairing per XCD;
// both LDS reductions atomic-free via per-chh partial regions (plain stores).
// R28 cleanups only: f32x4 reduce stores + vectorized epilogue reads.
constexpr int WT = 40;            // tile w-columns, covers global w in [wb-3, wb+36]
constexpr int RSTRIDE = WT * 128; // 5120 bytes per tile row
constexpr int OFFB = 14256;       // bytes per s_off region ([27][2][66] f32)

template <bool L2>
__global__ __launch_bounds__(512, 2) void fused_deform(
    const __hip_bfloat16* __restrict__ src, const __hip_bfloat16* __restrict__ owAk,
    const float* __restrict__ obias, const __hip_bfloat16* __restrict__ wAk,
    const float* __restrict__ xres, float* __restrict__ outf,
    __hip_bfloat16* __restrict__ ycl)
{
    __shared__ __align__(16) char s_mem[6 * RSTRIDE + 2 * OFFB];
    short* s_tile = (short*)s_mem;                            // swizzled tile [6][40][64ch]
    float* sp0    = (float*)(s_mem + 6 * RSTRIDE);            // chh=0 partials -> canonical s_off
    float* sp1    = (float*)(s_mem + 6 * RSTRIDE + OFFB);     // chh=1 partials
    float* s_off  = sp0;                                      // after merge
    float* red0 = (float*)s_mem;                              // [64][68] chh=0 partials (aliases tile)
    float* red1 = (float*)s_mem + 64 * 68;                    // [64][68] chh=1 partials

    int tid = threadIdx.x;
    int wv = tid >> 6, lane = tid & 63, l15 = lane & 15, l4 = lane >> 4;
    int nf = wv & 3, chh = wv >> 2;

    // ---- balanced plane-pair -> XCD decode ----
    int bi = blockIdx.x;
    int xcd = bi & 7, idx = bi >> 3;          // idx in [0,64)
    int jgrp = xcd >> 1, whalf = xcd & 1;     // job = (b, t-pair); w-half per XCD
    int b = jgrp >> 1;
    int h2 = idx & 31;                        // h-pair index
    int tsel = (idx >> 5) & 1;                // per-CU light/heavy interleave
    int t = ((jgrp & 1) << 1) + tsel;         // t-pair {0,1} or {2,3}
    int h0 = h2 * 2;
    int wb = whalf * 32;

    int pl = nf * 16 + l15;               // local position 0..63 (2 rows x 32 w)
    int prow = pl >> 5, pcol = pl & 31;
    int hr = h0 + prow;                   // this lane's output h row
    int p  = wb + pcol;                   // global w position
    int cbase = chh * 32 + l4 * 8;        // channel slice (MFMA K slice)
    int ktlo = (t == 0) ? 1 : 0, kthi = (t == 3) ? 2 : 3;

    const __hip_bfloat16* xb = src + ((size_t)b << 20);

    auto stage = [&](int kt) {
        int tt = t + kt - 1;   // valid by loop range
        const __hip_bfloat16* xt = xb + ((size_t)tt << 18);
        for (int i = tid; i < 6 * WT * 8; i += 512) {
            int r = i / (WT * 8), v = i - r * (WT * 8);
            int wl = v >> 3, ss = v & 7;
            int hh = h0 - 2 + r;
            int wg = wb - 3 + wl;
            bf16x8 val = {0, 0, 0, 0, 0, 0, 0, 0};
            if ((unsigned)hh < 64u && (unsigned)wg < 64u)
                val = *reinterpret_cast<const bf16x8*>(xt + ((hh * 64 + wg) << 6) + ss * 8);
            int byte = (r * RSTRIDE + wl * 128 + ss * 16) ^ ((wl & 7) << 4);
            *reinterpret_cast<bf16x8*>((char*)s_tile + byte) = val;
        }
    };
    auto ldread = [&](int sl, int wg) -> bf16x8 {   // wg = clamped global w (in window)
        int wl = wg - (wb - 3);
        int byte = (sl * RSTRIDE + wl * 128 + cbase * 2) ^ ((wl & 7) << 4);
        return *reinterpret_cast<const bf16x8*>((const char*)s_tile + byte);
    };

    // ================= pass A: offset conv (rolled taps) =================
    f32x4 cacc[4];
    #pragma unroll
    for (int mf = 0; mf < 4; ++mf) cacc[mf] = (f32x4){0.f, 0.f, 0.f, 0.f};

    for (int kt = ktlo; kt < kthi; ++kt) {
        __syncthreads();
        stage(kt);
        __syncthreads();
        #pragma clang loop unroll(disable)
        for (int rr = 0; rr < 9; ++rr) {
            int kh = rr / 3, kw = rr - kh * 3, tap = kt * 9 + rr;
            int ws = p + kw - 1;
            int wsc = min(max(ws, 0), 63);
            bf16x8 bv = ldread(prow + kh + 1, wsc);   // rows h0-1..h0+3 -> tile 1..4(+prow)
            if ((unsigned)ws >= 64u) bv = (bf16x8){0, 0, 0, 0, 0, 0, 0, 0};
            const __hip_bfloat16* ab = owAk + ((tap * 2 + chh) << 11) + (l15 << 5) + (l4 << 3);
            #pragma unroll
            for (int mf = 0; mf < 4; ++mf) {
                bf16x8 af = *reinterpret_cast<const bf16x8*>(ab + (mf << 9));
                cacc[mf] = __builtin_amdgcn_mfma_f32_16x16x32_bf16(af, bv, cacc[mf], 0, 0, 0);
            }
        }
    }
    // ---- atomic-free s_off reduction: plain stores to per-chh partial region ----
    {
        float* sp = chh ? sp1 : sp0;
        #pragma unroll
        for (int mf = 0; mf < 4; ++mf)
            #pragma unroll
            for (int jj = 0; jj < 4; ++jj) {
                int o = mf * 16 + l4 * 4 + jj;
                if (o < OFFc) sp[(o >> 1) * 132 + (o & 1) * 66 + pl] = cacc[mf][jj];
            }
    }
    __syncthreads();
    // ---- merge: s_off = sp0 + sp1 + bias (pad entries garbage, never read) ----
    for (int i = tid; i < KVc * 2 * 66; i += 512) {
        int k = i / 132, rem = i - k * 132, jo = rem / 66;
        sp0[i] = sp0[i] + sp1[i] + obias[2 * k + jo];
    }

    // ================= pass B: deformable conv (rolled x2, reverse kt) =================
    f32x4 dacc[4];
    #pragma unroll
    for (int mf = 0; mf < 4; ++mf) dacc[mf] = (f32x4){0.f, 0.f, 0.f, 0.f};

    unsigned badmask = 0;

    for (int kt = kthi - 1; kt >= ktlo; --kt) {
        __syncthreads();     // first iter: guards s_off merge; tile already holds kthi-1
        if (kt != kthi - 1) {
            stage(kt);
            __syncthreads();
        }
        #pragma clang loop unroll_count(2)
        for (int rr = 0; rr < 9; ++rr) {
            int kh = rr / 3, kw = rr - kh * 3, tap = kt * 9 + rr;
            float dh = s_off[tap * 132 + pl];
            float dw = s_off[tap * 132 + 66 + pl];
            float hs  = (float)(hr + kh - 1) + dh;
            float wsf = (float)(p + kw - 1) + dw;
            float fh = floorf(hs), fw = floorf(wsf);
            int hfl = (int)fh, w0 = (int)fw;
            float lh = hs - fh, lw = wsf - fw;
            float q0 = (1.f - lw) * (((unsigned)w0 < 64u) ? 1.f : 0.f);
            float q1 = lw         * (((unsigned)(w0 + 1) < 64u) ? 1.f : 0.f);
            int wc0 = min(max(w0, 0), 63), wc1 = min(max(w0 + 1, 0), 63);
            int r0 = hfl - (h0 - 2);
            int r0c = min(max(r0, 0), 4);
            badmask |= ((r0 != r0c) ? 1u : 0u) << tap;
            bf16x8 g0 = ldread(r0c, wc0),     g1 = ldread(r0c, wc1);
            bf16x8 g2 = ldread(r0c + 1, wc0), g3 = ldread(r0c + 1, wc1);
            float cf0 = (1.f - lh) * q0, cf1 = (1.f - lh) * q1;
            float cf2 = lh * q0,         cf3 = lh * q1;
            bf16x8 bfrag;
            #pragma unroll
            for (int jj = 0; jj < 8; ++jj) {
                float s = cf0 * bf2f(g0[jj]) + cf1 * bf2f(g1[jj])
                        + cf2 * bf2f(g2[jj]) + cf3 * bf2f(g3[jj]);
                bfrag[jj] = f2bf(s);
            }
            const __hip_bfloat16* ab = wAk + ((tap * 2 + chh) << 11) + (l15 << 5) + (l4 << 3);
            #pragma unroll
            for (int mf = 0; mf < 4; ++mf) {
                bf16x8 af = *reinterpret_cast<const bf16x8*>(ab + (mf << 9));
                dacc[mf] = __builtin_amdgcn_mfma_f32_16x16x32_bf16(af, bfrag, dacc[mf], 0, 0, 0);
            }
        }
    }

    // ---- exact correction for window misses (cold; never taken for ~0.02-scale offsets) ----
    if (__any((int)(badmask != 0u))) {
        for (int kt = ktlo; kt < kthi; ++kt) {
            int tt = t + kt - 1;
            const __hip_bfloat16* xt = xb + ((size_t)tt << 18);
            #pragma clang loop unroll(disable)
            for (int rr = 0; rr < 9; ++rr) {
                int tap = kt * 9 + rr;
                if (!__any((int)((badmask >> tap) & 1u))) continue;
                int kh = rr / 3, kw = rr - kh * 3;
                float dh = s_off[tap * 132 + pl];
                float dw = s_off[tap * 132 + 66 + pl];
                float hs  = (float)(hr + kh - 1) + dh;
                float wsf = (float)(p + kw - 1) + dw;
                float fh = floorf(hs), fw = floorf(wsf);
                int hfl = (int)fh, w0 = (int)fw;
                float lh = hs - fh, lw = wsf - fw;
                float q0 = (1.f - lw) * (((unsigned)w0 < 64u) ? 1.f : 0.f);
                float q1 = lw         * (((unsigned)(w0 + 1) < 64u) ? 1.f : 0.f);
                int wc0 = min(max(w0, 0), 63), wc1 = min(max(w0 + 1, 0), 63);
                int r0 = hfl - (h0 - 2);
                int r0c = min(max(r0, 0), 4);
                bool bad = ((badmask >> tap) & 1u) != 0u;
                float u0 = (1.f - lh) * (((unsigned)hfl < 64u) ? 1.f : 0.f);
                float u1 = lh         * (((unsigned)(hfl + 1) < 64u) ? 1.f : 0.f);
                int hc0 = min(max(hfl, 0), 63), hc1 = min(max(hfl + 1, 0), 63);
                bf16x8 tg0 = *reinterpret_cast<const bf16x8*>(xt + ((hc0 * 64 + wc0) << 6) + cbase);
                bf16x8 tg1 = *reinterpret_cast<const bf16x8*>(xt + ((hc0 * 64 + wc1) << 6) + cbase);
                bf16x8 tg2 = *reinterpret_cast<const bf16x8*>(xt + ((hc1 * 64 + wc0) << 6) + cbase);
                bf16x8 tg3 = *reinterpret_cast<const bf16x8*>(xt + ((hc1 * 64 + wc1) << 6) + cbase);
                int ra0 = h0 - 2 + r0c, ra1 = ra0 + 1;
                float m0 = ((unsigned)ra0 < 64u) ? 1.f : 0.f;
                float m1 = ((unsigned)ra1 < 64u) ? 1.f : 0.f;
                int rc0 = min(max(ra0, 0), 63), rc1 = min(max(ra1, 0), 63);
                bf16x8 ag0 = *reinterpret_cast<const bf16x8*>(xt + ((rc0 * 64 + wc0) << 6) + cbase);
                bf16x8 ag1 = *reinterpret_cast<const bf16x8*>(xt + ((rc0 * 64 + wc1) << 6) + cbase);
                bf16x8 ag2 = *reinterpret_cast<const bf16x8*>(xt + ((rc1 * 64 + wc0) << 6) + cbase);
                bf16x8 ag3 = *reinterpret_cast<const bf16x8*>(xt + ((rc1 * 64 + wc1) << 6) + cbase);
                bf16x8 bfrag;
                #pragma unroll
                for (int jj = 0; jj < 8; ++jj) {
                    float ft = u0 * (q0 * bf2f(tg0[jj]) + q1 * bf2f(tg1[jj]))
                             + u1 * (q0 * bf2f(tg2[jj]) + q1 * bf2f(tg3[jj]));
                    float fa = (1.f - lh) * m0 * (q0 * bf2f(ag0[jj]) + q1 * bf2f(ag1[jj]))
                             + lh * m1 * (q0 * bf2f(ag2[jj]) + q1 * bf2f(ag3[jj]));
                    bfrag[jj] = f2bf(bad ? (ft - fa) : 0.f);
                }
                const __hip_bfloat16* ab = wAk + ((tap * 2 + chh) << 11) + (l15 << 5) + (l4 << 3);
                #pragma unroll
                for (int mf = 0; mf < 4; ++mf) {
                    bf16x8 af = *reinterpret_cast<const bf16x8*>(ab + (mf << 9));
                    dacc[mf] = __builtin_amdgcn_mfma_f32_16x16x32_bf16(af, bfrag, dacc[mf], 0, 0, 0);
                }
            }
        }
    }

    // ---- atomic-free reduce: per-chh partial regions, f32x4 stores (tile + s_off dead) ----
    __syncthreads();                       // all tile / s_off reads complete
    {
        float* red = chh ? red1 : red0;
        #pragma unroll
        for (int mf = 0; mf < 4; ++mf)
            *reinterpret_cast<f32x4*>(&red[pl * 68 + mf * 16 + l4 * 4]) = dacc[mf];
    }
    __syncthreads();

    // ---- fused epilogue (sum the two chh regions, vectorized reads) ----
    if (!L2) {
        // leaky-relu + channel-last bf16 store (64 pos x 64 ch)
        int pp = tid >> 3, o8 = (tid & 7) << 3;
        int er = pp >> 5, ew = pp & 31;
        __hip_bfloat16* dst = ycl + ((((size_t)b * Tc + t) * HW + (h0 + er) * 64 + wb + ew) << 6) + o8;
        bf16x8 o8v;
        #pragma unroll
        for (int q = 0; q < 2; ++q) {
            f32x4 v0 = *reinterpret_cast<const f32x4*>(&red0[pp * 68 + o8 + q * 4]);
            f32x4 v1 = *reinterpret_cast<const f32x4*>(&red1[pp * 68 + o8 + q * 4]);
            #pragma unroll
            for (int jj = 0; jj < 4; ++jj) {
                float v = v0[jj] + v1[jj];
                v = v >= 0.f ? v : 0.1f * v;
                o8v[q * 4 + jj] = f2bf(v);
            }
        }
        *reinterpret_cast<bf16x8*>(dst) = o8v;
    } else {
        // residual add + fp32 channel-first store
        int o = tid >> 3, pg = (tid & 7) << 3;   // 8 positions per thread, same row
        int er = pg >> 5, ew = pg & 31;
        size_t base = ((size_t)(b * Cc + o) * Tc + t) * HW + (h0 + er) * 64 + wb + ew;
        #pragma unroll
        for (int q = 0; q < 2; ++q) {
            f32x4 r, xv = *reinterpret_cast<const f32x4*>(xres + base + q * 4);
            #pragma unroll
            for (int jj = 0; jj < 4; ++jj) {
                int i = (pg + q * 4 + jj) * 68 + o;
                r[jj] = red0[i] + red1[i] + xv[jj];
            }
            *reinterpret_cast<f32x4*>(outf + base + q * 4) = r;
        }
    }
}

extern "C" void kernel_launch(void* const* d_in, const int* in_sizes, int n_in,
                              void* d_out, int out_size, void* d_ws, size_t ws_size,
                              hipStream_t stream)
{
    const float* x   = (const float*)d_in[0];
    const float* w0  = (const float*)d_in[1];
    const float* ow0 = (const float*)d_in[2];
    const float* ob0 = (const float*)d_in[3];
    const float* w1  = (const float*)d_in[4];
    const float* ow1 = (const float*)d_in[5];
    const float* ob1 = (const float*)d_in[6];
    float* out = (float*)d_out;

    __hip_bfloat16* xcl  = (__hip_bfloat16*)d_ws;
    __hip_bfloat16* ycl  = xcl  + (size_t)Bc * THW * 64;
    __hip_bfloat16* owA0 = ycl  + (size_t)Bc * THW * 64;
    __hip_bfloat16* owA1 = owA0 + (size_t)216 * 512;
    __hip_bfloat16* wA0  = owA1 + (size_t)216 * 512;
    __hip_bfloat16* wA1  = wA0  + (size_t)216 * 512;

    w_prep4<<<1728, 256, 0, stream>>>(ow0, ow1, w0, w1, owA0, owA1, wA0, wA1);
    cast_cl<<<512, 256, 0, stream>>>(x, xcl);

    fused_deform<false><<<512, 512, 0, stream>>>(xcl, owA0, ob0, wA0, nullptr, nullptr, ycl);
    fused_deform<true><<<512, 512, 0, stream>>>(ycl, owA1, ob1, wA1, x, out, nullptr);
}